// Round 16
// baseline (79.555 us; speedup 1.0000x reference)
//
#include <hip/hip_runtime.h>
#include <stdint.h>

// Y = tanh(X @ W + b):  M=65536 (8*64*128), K=512, N=512, all fp32.
// R16 = R15 (one-shot A-staging, zero-barrier K-loop, 72us) with a 32-row
// M-tile for 3-blocks/CU residency.
// R15 post-mortem: MFMA-busy time == the 13.8us aggregate MFMA floor; the
// loss is HBM phase burstiness (prologue read / L2 K-loop / epilogue write
// serialized per block, only 2 resident: acc 128 AGPR + 100 VGPR = 228).
// Halving M-tile: acc 64 AGPR, VGPR ~90 -> ~154 <= 170 @ (256,3) -> 3
// blocks/CU; finer granularity interleaves the HBM read/write streams.
// Cost: B-image L2 traffic 2x (1GB aggregate = 128MB/XCD ~ 30us @ 4.3TB/s
// per-XCD) -- under 50% of that pipe, not binding.
// Swizzles unchanged in form (R15 measured 0 conflicts): A chunk^row both
// sides; B never in LDS (fragment-ordered L2-hot image, coalesced 1KB loads).

typedef short bf16x8 __attribute__((ext_vector_type(8)));
typedef float f32x16 __attribute__((ext_vector_type(16)));

#define KTOT 512
#define NTOT 512
#define WT_BYTES   524288ull      // 512*512*2
#define WS_NEEDED  WT_BYTES

__device__ __forceinline__ uint32_t pk2(float a, float b) {
  uint16_t lo = __builtin_bit_cast(uint16_t, (__bf16)a);   // RNE
  uint16_t hi = __builtin_bit_cast(uint16_t, (__bf16)b);
  return (uint32_t)lo | ((uint32_t)hi << 16);
}

__device__ __forceinline__ float fast_tanh(float z) {
  float t = __builtin_amdgcn_exp2f(z * 2.8853900817779268f);
  return 1.0f - 2.0f * __builtin_amdgcn_rcpf(t + 1.0f);
}

#define MFMA(A, B, C) __builtin_amdgcn_mfma_f32_32x32x16_bf16(A, B, C, 0, 0, 0)

// ---- pass 1: W fp32 [k][n] -> bf16 fragment-order image (as R15) ----
// 16B chunk c: lane=c&63, nf=(c>>6)&3, k16=(c>>8)&31, wq=c>>13.
// col = wq*128 + nf*32 + (lane&31); k = k16*16 + (lane>>5)*8 + [0..7].
__global__ __launch_bounds__(256)
void cvtW_kernel(const float* __restrict__ W, uint8_t* __restrict__ Wt) {
  const int c    = blockIdx.x * 256 + threadIdx.x;   // 0..32767
  const int lane = c & 63;
  const int nf   = (c >> 6) & 3;
  const int k16  = (c >> 8) & 31;
  const int wq   = c >> 13;
  const int col  = wq * 128 + nf * 32 + (lane & 31);
  const int kb   = k16 * 16 + (lane >> 5) * 8;
  float e[8];
#pragma unroll
  for (int i = 0; i < 8; ++i) e[i] = W[(size_t)(kb + i) * NTOT + col];
  *(uint4*)(Wt + (size_t)c * 16) =
      make_uint4(pk2(e[0], e[1]), pk2(e[2], e[3]),
                 pk2(e[4], e[5]), pk2(e[6], e[7]));
}

// ---------------- pass 2: one-shot-staged GEMM + bias + tanh ----------------
__global__ __launch_bounds__(256, 3)
void hotdd_fused(const float* __restrict__ X, const uint8_t* __restrict__ Wt,
                 const float* __restrict__ Bv, float* __restrict__ Y) {
  __shared__ uint8_t Ab[32768];   // A panel [32 rows][512 k] bf16, swizzled:
                                  // 16B chunk c of row r stored at slot c ^ r

  const int bm   = blockIdx.x;          // 0..2047 (32-row strips)
  const int tid  = threadIdx.x;
  const int lane = tid & 63;
  const int wv   = tid >> 6;
  const int lo5  = lane & 31;
  const int hi1  = lane >> 5;

#define SEP() asm volatile("" ::: "memory")
#define VM(N) asm volatile("s_waitcnt vmcnt(" #N ")" ::: "memory")

  // ==== prologue: stage A panel (64KB fp32 -> 32KB bf16 LDS), once ====
  // batch B covers fp32 elems [B*4096, +4096): thread loads 4 float4s at
  // q = Xs + B*4096 + tid*4 (+1024 apart) -> row = 8B + 2i + (tid>>7),
  // col = (tid&127)*4 -> chunk = (tid>>1)&63, half = tid&1.
  const float* Xs = X + (size_t)bm * (32 * KTOT);
  const int chunkT = (tid >> 1) & 63;
  const int halfT  = tid & 1;
  const int rbT    = tid >> 7;

  float4 p00, p01, p02, p03, p10, p11, p12, p13;

#define LOADP(R0, R1, R2, R3, B) do {                                         \
    const float* q_ = Xs + (size_t)(B) * 4096 + tid * 4;                      \
    R0 = *(const float4*)q_;          R1 = *(const float4*)(q_ + 1024);       \
    R2 = *(const float4*)(q_ + 2048); R3 = *(const float4*)(q_ + 3072);       \
    SEP();                                                                    \
  } while (0)

#define CVTP1(R, J) do {                                                      \
    const int row_ = 2 * (J) + rbT;                                           \
    *(uint2*)(Ab + row_ * 1024 + ((chunkT ^ row_) << 4) + halfT * 8) =        \
        make_uint2(pk2(R.x, R.y), pk2(R.z, R.w));                             \
  } while (0)
#define CVTP(R0, R1, R2, R3, B) do {                                          \
    CVTP1(R0, 4 * (B));     CVTP1(R1, 4 * (B) + 1);                           \
    CVTP1(R2, 4 * (B) + 2); CVTP1(R3, 4 * (B) + 3);  SEP();                   \
  } while (0)

  LOADP(p00, p01, p02, p03, 0);
  LOADP(p10, p11, p12, p13, 1);
  VM(4); CVTP(p00, p01, p02, p03, 0); LOADP(p00, p01, p02, p03, 2);
  VM(4); CVTP(p10, p11, p12, p13, 1); LOADP(p10, p11, p12, p13, 3);
  VM(4); CVTP(p00, p01, p02, p03, 2);
  VM(0); CVTP(p10, p11, p12, p13, 3);

  // ==== B prefetch bootstrap ====
  const uint8_t* pBw = Wt + (size_t)wv * 131072 + lane * 16;
  bf16x8 e0, e1, e2, e3, o0, o1, o2, o3, f0, f1, f2, f3;

#define LOADB(S0, S1, S2, S3, T) do {                                         \
    const uint8_t* q_ = pBw + (size_t)(T) * 4096;                             \
    S0 = *(const bf16x8*)q_;            S1 = *(const bf16x8*)(q_ + 1024);     \
    S2 = *(const bf16x8*)(q_ + 2048);   S3 = *(const bf16x8*)(q_ + 3072);     \
    SEP();                                                                    \
  } while (0)

  LOADB(e0, e1, e2, e3, 0);
  LOADB(o0, o1, o2, o3, 1);
  __syncthreads();                 // all A writes visible; one barrier total

  // ==== K-loop: 32 k16 steps, no barriers, no LDS writes ====
  f32x16 c0 = {}, c1 = {}, c2 = {}, c3 = {};
  const int ardA = lo5 << 10;            // row lo5 (all 32 rows shared)

#define COMP(T, S0, S1, S2, S3) do {                                          \
    const int cb_ = (((((T) << 1) | hi1)) ^ lo5) << 4;                        \
    bf16x8 fa = *(const bf16x8*)(Ab + ardA + cb_);                            \
    c0 = MFMA(fa, S0, c0);  c1 = MFMA(fa, S1, c1);                            \
    c2 = MFMA(fa, S2, c2);  c3 = MFMA(fa, S3, c3);                            \
  } while (0)

#pragma unroll 1
  for (int t = 0; t < 30; t += 3) {      // sets rotate e,o,f; 2-step B slack
    LOADB(f0, f1, f2, f3, t + 2);  VM(8);  COMP(t,     e0, e1, e2, e3);
    LOADB(e0, e1, e2, e3, t + 3);  VM(8);  COMP(t + 1, o0, o1, o2, o3);
    LOADB(o0, o1, o2, o3, t + 4);  VM(8);  COMP(t + 2, f0, f1, f2, f3);
  }
  VM(4);  COMP(30, e0, e1, e2, e3);
  VM(0);  COMP(31, o0, o1, o2, o3);

  // ==== epilogue: bias + tanh + fp32 store ====
  const int colb = wv * 128 + lo5;
  const float bv0 = Bv[colb];
  const float bv1 = Bv[colb + 32];
  const float bv2 = Bv[colb + 64];
  const float bv3 = Bv[colb + 96];
  const size_t rowbase = (size_t)bm * 32 + (hi1 << 2);

#define EPI(ACC, NF, BV) do {                                                 \
    _Pragma("unroll")                                                         \
    for (int r = 0; r < 16; ++r) {                                            \
      const size_t row_ = rowbase + (r & 3) + ((r >> 2) << 3);                \
      Y[row_ * NTOT + colb + (NF) * 32] = fast_tanh((ACC)[r] + (BV));         \
    }                                                                         \
  } while (0)

  EPI(c0, 0, bv0);  EPI(c1, 1, bv1);
  EPI(c2, 2, bv2);  EPI(c3, 3, bv3);
}

// ---------------- fallback: R1 kernel (146us), used if ws too small ----------
struct Regs {
  float4 a0,a1,a2,a3,a4,a5,a6,a7;
  float4 u0,u1,u2,u3;
  float4 v0,v1,v2,v3;
};

__global__ __launch_bounds__(256, 2)
void hotdd_fallback(const float* __restrict__ X, const float* __restrict__ W,
                    const float* __restrict__ Bv, float* __restrict__ Y) {
  __shared__ char Ab[128 * 64 * 2];
  __shared__ char Bb[128 * 64 * 2];
  const int d  = blockIdx.x;
  const int bm = ((d >> 5) << 3) | (d & 7);
  const int bn = (d >> 3) & 3;
  const int tid  = threadIdx.x;
  const int lane = tid & 63;
  const int wv   = tid >> 6;
  const int wr   = (wv >> 1) * 64;
  const int wc   = (wv & 1) * 64;
  const int lo5  = lane & 31;
  const int hi1  = lane >> 5;
  const int rs   = lo5 & 7;
  const int am   = tid >> 1;
  const int ah   = tid & 1;
  const int amz  = am & 7;
  const int abase = am * 128;
  const float* Ag = X + (size_t)(bm * 128 + am) * KTOT + ah * 32;
  const int kp = lo5;
  const int ng = wv * 32 + hi1 * 16;
  const float* Bg = W + (size_t)(2 * kp) * NTOT + bn * 128 + ng;

#define LOADR(R, K0) do {                                                     \
    const float* ap_ = Ag + (K0);                                             \
    R.a0 = *(const float4*)(ap_ +  0); R.a1 = *(const float4*)(ap_ +  4);     \
    R.a2 = *(const float4*)(ap_ +  8); R.a3 = *(const float4*)(ap_ + 12);     \
    R.a4 = *(const float4*)(ap_ + 16); R.a5 = *(const float4*)(ap_ + 20);     \
    R.a6 = *(const float4*)(ap_ + 24); R.a7 = *(const float4*)(ap_ + 28);     \
    const float* bp_ = Bg + (size_t)(K0) * NTOT;                              \
    R.u0 = *(const float4*)(bp_ +  0); R.u1 = *(const float4*)(bp_ +  4);     \
    R.u2 = *(const float4*)(bp_ +  8); R.u3 = *(const float4*)(bp_ + 12);     \
    R.v0 = *(const float4*)(bp_ + NTOT +  0); R.v1 = *(const float4*)(bp_ + NTOT +  4); \
    R.v2 = *(const float4*)(bp_ + NTOT +  8); R.v3 = *(const float4*)(bp_ + NTOT + 12); \
  } while (0)

#define ASTF(R, J, P, Q)                                                      \
    *(uint4*)(Ab + abase + (((((ah << 2) + (J)) ^ amz)) << 4)) =              \
      make_uint4(pk2(R.P.x, R.P.y), pk2(R.P.z, R.P.w),                        \
                 pk2(R.Q.x, R.Q.y), pk2(R.Q.z, R.Q.w));
#define BSTF(R, I, UV, C)                                                     \
    *(uint32_t*)(Bb + (ng + (I)) * 128 + ((kp << 2) ^ (((I) & 7) << 4))) =    \
      pk2(R.u##UV.C, R.v##UV.C);

#define STORERF(R) do {                                                       \
    ASTF(R, 0, a0, a1) ASTF(R, 1, a2, a3) ASTF(R, 2, a4, a5) ASTF(R, 3, a6, a7)\
    BSTF(R, 0, 0, x) BSTF(R, 1, 0, y) BSTF(R, 2, 0, z) BSTF(R, 3, 0, w)       \
    BSTF(R, 4, 1, x) BSTF(R, 5, 1, y) BSTF(R, 6, 1, z) BSTF(R, 7, 1, w)       \
    BSTF(R, 8, 2, x) BSTF(R, 9, 2, y) BSTF(R,10, 2, z) BSTF(R,11, 2, w)       \
    BSTF(R,12, 3, x) BSTF(R,13, 3, y) BSTF(R,14, 3, z) BSTF(R,15, 3, w)       \
  } while (0)

  f32x16 acc00 = {}, acc01 = {}, acc10 = {}, acc11 = {};
  const char* Ard0 = Ab + (wr + lo5) * 128;
  const char* Ard1 = Ard0 + 32 * 128;
  const char* Brd0 = Bb + (wc + lo5) * 128;
  const char* Brd1 = Brd0 + 32 * 128;

#define MFMA_PHASE_F() do {                                                   \
    _Pragma("unroll")                                                         \
    for (int kk = 0; kk < 4; ++kk) {                                          \
      const int sb = ((((kk << 1) | hi1) ^ rs) << 4);                         \
      bf16x8 fa0 = *(const bf16x8*)(Ard0 + sb);                               \
      bf16x8 fa1 = *(const bf16x8*)(Ard1 + sb);                               \
      bf16x8 fb0 = *(const bf16x8*)(Brd0 + sb);                               \
      bf16x8 fb1 = *(const bf16x8*)(Brd1 + sb);                               \
      acc00 = MFMA(fa0, fb0, acc00);  acc01 = MFMA(fa0, fb1, acc01);          \
      acc10 = MFMA(fa1, fb0, acc10);  acc11 = MFMA(fa1, fb1, acc11);          \
    }                                                                         \
  } while (0)

  Regs r0, r1;
  LOADR(r0, 0);
#pragma unroll 1
  for (int s = 0; s < 8; s += 2) {
    STORERF(r0);
    __syncthreads();
    LOADR(r1, (s + 1) * 64);
    MFMA_PHASE_F();
    __syncthreads();
    STORERF(r1);
    __syncthreads();
    if (s + 2 < 8) LOADR(r0, (s + 2) * 64);
    MFMA_PHASE_F();
    __syncthreads();
  }

  const int gn0 = bn * 128 + wc + lo5;
  const int gn1 = gn0 + 32;
  const float bv0 = Bv[gn0];
  const float bv1 = Bv[gn1];

#define EPIF(ACC, MI, GN, BVAL) do {                                          \
    _Pragma("unroll")                                                         \
    for (int r = 0; r < 16; ++r) {                                            \
      const int mloc = wr + (MI) * 32 + (hi1 << 2) + ((r >> 2) << 3) + (r & 3);\
      Y[(size_t)(bm * 128 + mloc) * NTOT + (GN)] = fast_tanh((ACC)[r] + (BVAL));\
    }                                                                         \
  } while (0)

  EPIF(acc00, 0, gn0, bv0);
  EPIF(acc01, 0, gn1, bv1);
  EPIF(acc10, 1, gn0, bv0);
  EPIF(acc11, 1, gn1, bv1);
}

extern "C" void kernel_launch(void* const* d_in, const int* in_sizes, int n_in,
                              void* d_out, int out_size, void* d_ws, size_t ws_size,
                              hipStream_t stream) {
  (void)in_sizes; (void)n_in; (void)out_size;
  const float* X = (const float*)d_in[0];
  const float* W = (const float*)d_in[1];
  const float* b = (const float*)d_in[2];
  float* Y = (float*)d_out;
  if (ws_size >= WS_NEEDED) {
    uint8_t* Wt = (uint8_t*)d_ws;
    hipLaunchKernelGGL(cvtW_kernel, dim3(128),  dim3(256), 0, stream, W, Wt);
    hipLaunchKernelGGL(hotdd_fused, dim3(2048), dim3(256), 0, stream, X, Wt, b, Y);
  } else {
    hipLaunchKernelGGL(hotdd_fallback, dim3(2048), dim3(256), 0, stream, X, W, b, Y);
  }
}

// Round 17
// 77.905 us; speedup vs baseline: 1.0212x; 1.0212x over previous
//
#include <hip/hip_runtime.h>
#include <stdint.h>

// Y = tanh(X @ W + b):  M=65536 (8*64*128), K=512, N=512, all fp32.
// R17 = R15 geometry (64-row x N512 x K512 one-shot block, 72us best) with
// 8 WAVES / 512 THREADS: wave owns 64x64 (not 64x128).
// R16 lesson: B L2-stream scales as 1/M_tile (halving M doubled it, +8us).
// So keep M=64 (B per block 512KB, 2MB/CU unchanged) and get occupancy by
// splitting N 8 ways inside the block: acc 128->64 AGPR, VGPR ~60 ->
// combined <=128 @ __launch_bounds__(512,4) -> 2 blocks/CU = 16 waves/CU
// (2x R15) at IDENTICAL traffic. LDS 64KB x2 = 128 <= 160.
// Structure per wave-step: 2 coalesced 1KB B-loads (L2-hot fragment image)
// + 2 swizzled ds_read_b128 + 4 MFMA; VM(4) counted waits, no barriers in
// the K-loop, one __syncthreads total.

typedef short bf16x8 __attribute__((ext_vector_type(8)));
typedef float f32x16 __attribute__((ext_vector_type(16)));

#define KTOT 512
#define NTOT 512
#define WT_BYTES   524288ull      // 512*512*2
#define WS_NEEDED  WT_BYTES

__device__ __forceinline__ uint32_t pk2(float a, float b) {
  uint16_t lo = __builtin_bit_cast(uint16_t, (__bf16)a);   // RNE
  uint16_t hi = __builtin_bit_cast(uint16_t, (__bf16)b);
  return (uint32_t)lo | ((uint32_t)hi << 16);
}

__device__ __forceinline__ float fast_tanh(float z) {
  float t = __builtin_amdgcn_exp2f(z * 2.8853900817779268f);
  return 1.0f - 2.0f * __builtin_amdgcn_rcpf(t + 1.0f);
}

#define MFMA(A, B, C) __builtin_amdgcn_mfma_f32_32x32x16_bf16(A, B, C, 0, 0, 0)

// ---- pass 1: W fp32 [k][n] -> bf16 fragment-order image (as R15) ----
// 16B chunk c: lane=c&63, nf=(c>>6)&3, k16=(c>>8)&31, wq=c>>13.
// col = wq*128 + nf*32 + (lane&31); k = k16*16 + (lane>>5)*8 + [0..7].
__global__ __launch_bounds__(256)
void cvtW_kernel(const float* __restrict__ W, uint8_t* __restrict__ Wt) {
  const int c    = blockIdx.x * 256 + threadIdx.x;   // 0..32767
  const int lane = c & 63;
  const int nf   = (c >> 6) & 3;
  const int k16  = (c >> 8) & 31;
  const int wq   = c >> 13;
  const int col  = wq * 128 + nf * 32 + (lane & 31);
  const int kb   = k16 * 16 + (lane >> 5) * 8;
  float e[8];
#pragma unroll
  for (int i = 0; i < 8; ++i) e[i] = W[(size_t)(kb + i) * NTOT + col];
  *(uint4*)(Wt + (size_t)c * 16) =
      make_uint4(pk2(e[0], e[1]), pk2(e[2], e[3]),
                 pk2(e[4], e[5]), pk2(e[6], e[7]));
}

// ---------------- pass 2: one-shot-staged GEMM + bias + tanh ----------------
__global__ __launch_bounds__(512, 4)
void hotdd_fused(const float* __restrict__ X, const uint8_t* __restrict__ Wt,
                 const float* __restrict__ Bv, float* __restrict__ Y) {
  __shared__ uint8_t Ab[65536];   // A panel [64 rows][512 k] bf16, swizzled:
                                  // 16B chunk c of row r stored at slot c ^ r

  const int bm   = blockIdx.x;          // 0..1023 (64-row strips)
  const int tid  = threadIdx.x;         // 0..511
  const int lane = tid & 63;
  const int wv   = tid >> 6;            // 0..7
  const int lo5  = lane & 31;
  const int hi1  = lane >> 5;

#define SEP() asm volatile("" ::: "memory")
#define VM(N) asm volatile("s_waitcnt vmcnt(" #N ")" ::: "memory")

  // ==== prologue: stage A panel (128KB fp32 -> 64KB bf16 LDS), once ====
  // batch B covers elems [B*4096,+4096): thread loads 2 float4 at
  // q = Xs + B*4096 + tid*4 and +2048 -> rows B*8 + {0,4} + (tid>>7),
  // chunk = (tid>>1)&63, half = tid&1. 8 batches, 1 ping-pong reg pair.
  const float* Xs = X + (size_t)bm * (64 * KTOT);
  const int chunkT = (tid >> 1) & 63;
  const int halfT  = tid & 1;
  const int rbT    = tid >> 7;          // 0..3

  float4 q0, q1, r0, r1;

#define L2P(RA, RB, B) do {                                                   \
    const float* p_ = Xs + (size_t)(B) * 4096 + tid * 4;                      \
    RA = *(const float4*)p_;  RB = *(const float4*)(p_ + 2048);  SEP();       \
  } while (0)

#define C2P(RA, RB, B) do {                                                   \
    const int ra_ = (B) * 8 + rbT;                                            \
    *(uint2*)(Ab + ra_ * 1024 + ((chunkT ^ ra_) << 4) + halfT * 8) =          \
        make_uint2(pk2(RA.x, RA.y), pk2(RA.z, RA.w));                         \
    const int rb_ = (B) * 8 + 4 + rbT;                                        \
    *(uint2*)(Ab + rb_ * 1024 + ((chunkT ^ rb_) << 4) + halfT * 8) =          \
        make_uint2(pk2(RB.x, RB.y), pk2(RB.z, RB.w));                         \
    SEP();                                                                    \
  } while (0)

  L2P(q0, q1, 0);
  L2P(r0, r1, 1);
  VM(2); C2P(q0, q1, 0); L2P(q0, q1, 2);
  VM(2); C2P(r0, r1, 1); L2P(r0, r1, 3);
  VM(2); C2P(q0, q1, 2); L2P(q0, q1, 4);
  VM(2); C2P(r0, r1, 3); L2P(r0, r1, 5);
  VM(2); C2P(q0, q1, 4); L2P(q0, q1, 6);
  VM(2); C2P(r0, r1, 5); L2P(r0, r1, 7);
  VM(2); C2P(q0, q1, 6);
  VM(0); C2P(r0, r1, 7);

  // ==== B prefetch bootstrap (in flight across the barrier) ====
  // wave wv owns cols [wv*64, +64): image bytes (wv>>1)*131072 +
  // k16*4096 + (wv&1)*2048 + {0,1024} + lane*16.
  const uint8_t* pBw = Wt + (size_t)(wv >> 1) * 131072 + (wv & 1) * 2048
                          + lane * 16;
  bf16x8 e0, e1, o0, o1, f0, f1;

#define LOADB(S0, S1, T) do {                                                 \
    const uint8_t* p_ = pBw + (size_t)(T) * 4096;                             \
    S0 = *(const bf16x8*)p_;  S1 = *(const bf16x8*)(p_ + 1024);  SEP();       \
  } while (0)

  LOADB(e0, e1, 0);
  LOADB(o0, o1, 1);
  __syncthreads();                 // all A writes visible; one barrier total

  // ==== K-loop: 32 k16 steps, no barriers, no LDS writes ====
  f32x16 c00 = {}, c01 = {}, c10 = {}, c11 = {};
  const int ardA = lo5 << 10;            // row lo5
  const int ardB = (lo5 + 32) << 10;     // row lo5+32 (slot key ^32 -> ^512B)

#define COMP(T, S0, S1) do {                                                  \
    const int cb_ = (((((T) << 1) | hi1)) ^ lo5) << 4;                        \
    bf16x8 fa0 = *(const bf16x8*)(Ab + ardA + cb_);                           \
    bf16x8 fa1 = *(const bf16x8*)(Ab + ardB + (cb_ ^ 512));                   \
    c00 = MFMA(fa0, S0, c00);  c01 = MFMA(fa0, S1, c01);                      \
    c10 = MFMA(fa1, S0, c10);  c11 = MFMA(fa1, S1, c11);                      \
  } while (0)

#pragma unroll 1
  for (int t = 0; t < 30; t += 3) {      // sets rotate e,o,f; 2-step B slack
    LOADB(f0, f1, t + 2);  VM(4);  COMP(t,     e0, e1);
    LOADB(e0, e1, t + 3);  VM(4);  COMP(t + 1, o0, o1);
    LOADB(o0, o1, t + 4);  VM(4);  COMP(t + 2, f0, f1);
  }
  VM(2);  COMP(30, e0, e1);
  VM(0);  COMP(31, o0, o1);

  // ==== epilogue: bias + tanh + fp32 store ====
  const int colb = wv * 64 + lo5;
  const float bv0 = Bv[colb];
  const float bv1 = Bv[colb + 32];
  const size_t rowbase = (size_t)bm * 64 + (hi1 << 2);

#define EPI(ACC, MI, NF, BV) do {                                             \
    _Pragma("unroll")                                                         \
    for (int r = 0; r < 16; ++r) {                                            \
      const size_t row_ = rowbase + (MI) * 32 + (r & 3) + ((r >> 2) << 3);    \
      Y[row_ * NTOT + colb + (NF) * 32] = fast_tanh((ACC)[r] + (BV));         \
    }                                                                         \
  } while (0)

  EPI(c00, 0, 0, bv0);  EPI(c01, 0, 1, bv1);
  EPI(c10, 1, 0, bv0);  EPI(c11, 1, 1, bv1);
}

// ---------------- fallback: R1 kernel (146us), used if ws too small ----------
struct Regs {
  float4 a0,a1,a2,a3,a4,a5,a6,a7;
  float4 u0,u1,u2,u3;
  float4 v0,v1,v2,v3;
};

__global__ __launch_bounds__(256, 2)
void hotdd_fallback(const float* __restrict__ X, const float* __restrict__ W,
                    const float* __restrict__ Bv, float* __restrict__ Y) {
  __shared__ char Ab[128 * 64 * 2];
  __shared__ char Bb[128 * 64 * 2];
  const int d  = blockIdx.x;
  const int bm = ((d >> 5) << 3) | (d & 7);
  const int bn = (d >> 3) & 3;
  const int tid  = threadIdx.x;
  const int lane = tid & 63;
  const int wv   = tid >> 6;
  const int wr   = (wv >> 1) * 64;
  const int wc   = (wv & 1) * 64;
  const int lo5  = lane & 31;
  const int hi1  = lane >> 5;
  const int rs   = lo5 & 7;
  const int am   = tid >> 1;
  const int ah   = tid & 1;
  const int amz  = am & 7;
  const int abase = am * 128;
  const float* Ag = X + (size_t)(bm * 128 + am) * KTOT + ah * 32;
  const int kp = lo5;
  const int ng = wv * 32 + hi1 * 16;
  const float* Bg = W + (size_t)(2 * kp) * NTOT + bn * 128 + ng;

#define LOADR(R, K0) do {                                                     \
    const float* ap_ = Ag + (K0);                                             \
    R.a0 = *(const float4*)(ap_ +  0); R.a1 = *(const float4*)(ap_ +  4);     \
    R.a2 = *(const float4*)(ap_ +  8); R.a3 = *(const float4*)(ap_ + 12);     \
    R.a4 = *(const float4*)(ap_ + 16); R.a5 = *(const float4*)(ap_ + 20);     \
    R.a6 = *(const float4*)(ap_ + 24); R.a7 = *(const float4*)(ap_ + 28);     \
    const float* bp_ = Bg + (size_t)(K0) * NTOT;                              \
    R.u0 = *(const float4*)(bp_ +  0); R.u1 = *(const float4*)(bp_ +  4);     \
    R.u2 = *(const float4*)(bp_ +  8); R.u3 = *(const float4*)(bp_ + 12);     \
    R.v0 = *(const float4*)(bp_ + NTOT +  0); R.v1 = *(const float4*)(bp_ + NTOT +  4); \
    R.v2 = *(const float4*)(bp_ + NTOT +  8); R.v3 = *(const float4*)(bp_ + NTOT + 12); \
  } while (0)

#define ASTF(R, J, P, Q)                                                      \
    *(uint4*)(Ab + abase + (((((ah << 2) + (J)) ^ amz)) << 4)) =              \
      make_uint4(pk2(R.P.x, R.P.y), pk2(R.P.z, R.P.w),                        \
                 pk2(R.Q.x, R.Q.y), pk2(R.Q.z, R.Q.w));
#define BSTF(R, I, UV, C)                                                     \
    *(uint32_t*)(Bb + (ng + (I)) * 128 + ((kp << 2) ^ (((I) & 7) << 4))) =    \
      pk2(R.u##UV.C, R.v##UV.C);

#define STORERF(R) do {                                                       \
    ASTF(R, 0, a0, a1) ASTF(R, 1, a2, a3) ASTF(R, 2, a4, a5) ASTF(R, 3, a6, a7)\
    BSTF(R, 0, 0, x) BSTF(R, 1, 0, y) BSTF(R, 2, 0, z) BSTF(R, 3, 0, w)       \
    BSTF(R, 4, 1, x) BSTF(R, 5, 1, y) BSTF(R, 6, 1, z) BSTF(R, 7, 1, w)       \
    BSTF(R, 8, 2, x) BSTF(R, 9, 2, y) BSTF(R,10, 2, z) BSTF(R,11, 2, w)       \
    BSTF(R,12, 3, x) BSTF(R,13, 3, y) BSTF(R,14, 3, z) BSTF(R,15, 3, w)       \
  } while (0)

  f32x16 acc00 = {}, acc01 = {}, acc10 = {}, acc11 = {};
  const char* Ard0 = Ab + (wr + lo5) * 128;
  const char* Ard1 = Ard0 + 32 * 128;
  const char* Brd0 = Bb + (wc + lo5) * 128;
  const char* Brd1 = Brd0 + 32 * 128;

#define MFMA_PHASE_F() do {                                                   \
    _Pragma("unroll")                                                         \
    for (int kk = 0; kk < 4; ++kk) {                                          \
      const int sb = ((((kk << 1) | hi1) ^ rs) << 4);                         \
      bf16x8 fa0 = *(const bf16x8*)(Ard0 + sb);                               \
      bf16x8 fa1 = *(const bf16x8*)(Ard1 + sb);                               \
      bf16x8 fb0 = *(const bf16x8*)(Brd0 + sb);                               \
      bf16x8 fb1 = *(const bf16x8*)(Brd1 + sb);                               \
      acc00 = MFMA(fa0, fb0, acc00);  acc01 = MFMA(fa0, fb1, acc01);          \
      acc10 = MFMA(fa1, fb0, acc10);  acc11 = MFMA(fa1, fb1, acc11);          \
    }                                                                         \
  } while (0)

  Regs r0, r1;
  LOADR(r0, 0);
#pragma unroll 1
  for (int s = 0; s < 8; s += 2) {
    STORERF(r0);
    __syncthreads();
    LOADR(r1, (s + 1) * 64);
    MFMA_PHASE_F();
    __syncthreads();
    STORERF(r1);
    __syncthreads();
    if (s + 2 < 8) LOADR(r0, (s + 2) * 64);
    MFMA_PHASE_F();
    __syncthreads();
  }

  const int gn0 = bn * 128 + wc + lo5;
  const int gn1 = gn0 + 32;
  const float bv0 = Bv[gn0];
  const float bv1 = Bv[gn1];

#define EPIF(ACC, MI, GN, BVAL) do {                                          \
    _Pragma("unroll")                                                         \
    for (int r = 0; r < 16; ++r) {                                            \
      const int mloc = wr + (MI) * 32 + (hi1 << 2) + ((r >> 2) << 3) + (r & 3);\
      Y[(size_t)(bm * 128 + mloc) * NTOT + (GN)] = fast_tanh((ACC)[r] + (BVAL));\
    }                                                                         \
  } while (0)

  EPIF(acc00, 0, gn0, bv0);
  EPIF(acc01, 0, gn1, bv1);
  EPIF(acc10, 1, gn0, bv0);
  EPIF(acc11, 1, gn1, bv1);
}

extern "C" void kernel_launch(void* const* d_in, const int* in_sizes, int n_in,
                              void* d_out, int out_size, void* d_ws, size_t ws_size,
                              hipStream_t stream) {
  (void)in_sizes; (void)n_in; (void)out_size;
  const float* X = (const float*)d_in[0];
  const float* W = (const float*)d_in[1];
  const float* b = (const float*)d_in[2];
  float* Y = (float*)d_out;
  if (ws_size >= WS_NEEDED) {
    uint8_t* Wt = (uint8_t*)d_ws;
    hipLaunchKernelGGL(cvtW_kernel, dim3(128),  dim3(256), 0, stream, W, Wt);
    hipLaunchKernelGGL(hotdd_fused, dim3(1024), dim3(512), 0, stream, X, Wt, b, Y);
  } else {
    hipLaunchKernelGGL(hotdd_fallback, dim3(2048), dim3(256), 0, stream, X, W, b, Y);
  }
}

// Round 18
// 75.285 us; speedup vs baseline: 1.0567x; 1.0348x over previous
//
#include <hip/hip_runtime.h>
#include <stdint.h>

// Y = tanh(X @ W + b):  M=65536 (8*64*128), K=512, N=512, all fp32.
// R18 = R15 (best, 72.0us: one-shot A-staging, zero-barrier K-loop, 64-row
// block, 4 waves x 64x128) with B-PREFETCH DEPTH 4 (was 3 sets / 2-step
// slack). R15's residual stall: per-step issue ~80-100cy, 2-step slack
// ~160-200cy < L2 latency ~200-300cy -> every step exposed. R17 proved
// occupancy doesn't fix it (slack halved too -> worse); L2 BW is at ~20%
// of ceiling so it's pure latency -> fix with depth.
// 4 rotating B sets (e,o,f,g): steady VM(12) retires oldest step's 4 loads,
// 3-step slack ~240-300cy. +16 VGPR (total ~116+128AGPR=244 <= 256, same
// 2-block/CU class). Everything else identical to R15.

typedef short bf16x8 __attribute__((ext_vector_type(8)));
typedef float f32x16 __attribute__((ext_vector_type(16)));

#define KTOT 512
#define NTOT 512
#define WT_BYTES   524288ull      // 512*512*2
#define WS_NEEDED  WT_BYTES

__device__ __forceinline__ uint32_t pk2(float a, float b) {
  uint16_t lo = __builtin_bit_cast(uint16_t, (__bf16)a);   // RNE
  uint16_t hi = __builtin_bit_cast(uint16_t, (__bf16)b);
  return (uint32_t)lo | ((uint32_t)hi << 16);
}

__device__ __forceinline__ float fast_tanh(float z) {
  float t = __builtin_amdgcn_exp2f(z * 2.8853900817779268f);
  return 1.0f - 2.0f * __builtin_amdgcn_rcpf(t + 1.0f);
}

#define MFMA(A, B, C) __builtin_amdgcn_mfma_f32_32x32x16_bf16(A, B, C, 0, 0, 0)

// ---- pass 1: W fp32 [k][n] -> bf16 fragment-order image (as R15) ----
// 16B chunk c: lane=c&63, nf=(c>>6)&3, k16=(c>>8)&31, wq=c>>13.
// col = wq*128 + nf*32 + (lane&31); k = k16*16 + (lane>>5)*8 + [0..7].
__global__ __launch_bounds__(256)
void cvtW_kernel(const float* __restrict__ W, uint8_t* __restrict__ Wt) {
  const int c    = blockIdx.x * 256 + threadIdx.x;   // 0..32767
  const int lane = c & 63;
  const int nf   = (c >> 6) & 3;
  const int k16  = (c >> 8) & 31;
  const int wq   = c >> 13;
  const int col  = wq * 128 + nf * 32 + (lane & 31);
  const int kb   = k16 * 16 + (lane >> 5) * 8;
  float e[8];
#pragma unroll
  for (int i = 0; i < 8; ++i) e[i] = W[(size_t)(kb + i) * NTOT + col];
  *(uint4*)(Wt + (size_t)c * 16) =
      make_uint4(pk2(e[0], e[1]), pk2(e[2], e[3]),
                 pk2(e[4], e[5]), pk2(e[6], e[7]));
}

// ---------------- pass 2: one-shot-staged GEMM + bias + tanh ----------------
__global__ __launch_bounds__(256, 2)
void hotdd_fused(const float* __restrict__ X, const uint8_t* __restrict__ Wt,
                 const float* __restrict__ Bv, float* __restrict__ Y) {
  __shared__ uint8_t Ab[65536];   // A panel [64 rows][512 k] bf16, swizzled:
                                  // 16B chunk c of row r stored at slot c ^ r

  const int bm   = blockIdx.x;          // 0..1023 (64-row strips)
  const int tid  = threadIdx.x;
  const int lane = tid & 63;
  const int wv   = tid >> 6;
  const int lo5  = lane & 31;
  const int hi1  = lane >> 5;

#define SEP() asm volatile("" ::: "memory")
#define VM(N) asm volatile("s_waitcnt vmcnt(" #N ")" ::: "memory")

  // ==== prologue: stage A panel (128KB fp32 -> 64KB bf16 LDS), once ====
  const float* Xs = X + (size_t)bm * (64 * KTOT);
  const int chunkT = (tid >> 1) & 63;
  const int halfT  = tid & 1;
  const int rbT    = tid >> 7;

  float4 p00, p01, p02, p03, p10, p11, p12, p13;

#define LOADP(R0, R1, R2, R3, B) do {                                         \
    const float* q_ = Xs + (size_t)(B) * 4096 + tid * 4;                      \
    R0 = *(const float4*)q_;          R1 = *(const float4*)(q_ + 1024);       \
    R2 = *(const float4*)(q_ + 2048); R3 = *(const float4*)(q_ + 3072);       \
    SEP();                                                                    \
  } while (0)

#define CVTP1(R, J) do {                                                      \
    const int row_ = 2 * (J) + rbT;                                           \
    *(uint2*)(Ab + row_ * 1024 + ((chunkT ^ row_) << 4) + halfT * 8) =        \
        make_uint2(pk2(R.x, R.y), pk2(R.z, R.w));                             \
  } while (0)
#define CVTP(R0, R1, R2, R3, B) do {                                          \
    CVTP1(R0, 4 * (B));     CVTP1(R1, 4 * (B) + 1);                           \
    CVTP1(R2, 4 * (B) + 2); CVTP1(R3, 4 * (B) + 3);  SEP();                   \
  } while (0)

  LOADP(p00, p01, p02, p03, 0);
  LOADP(p10, p11, p12, p13, 1);
  VM(4); CVTP(p00, p01, p02, p03, 0); LOADP(p00, p01, p02, p03, 2);
  VM(4); CVTP(p10, p11, p12, p13, 1); LOADP(p10, p11, p12, p13, 3);
  VM(4); CVTP(p00, p01, p02, p03, 2); LOADP(p00, p01, p02, p03, 4);
  VM(4); CVTP(p10, p11, p12, p13, 3); LOADP(p10, p11, p12, p13, 5);
  VM(4); CVTP(p00, p01, p02, p03, 4); LOADP(p00, p01, p02, p03, 6);
  VM(4); CVTP(p10, p11, p12, p13, 5); LOADP(p10, p11, p12, p13, 7);
  VM(4); CVTP(p00, p01, p02, p03, 6);
  VM(0); CVTP(p10, p11, p12, p13, 7);

  // ==== B prefetch bootstrap: 3 steps in flight across the barrier ====
  const uint8_t* pBw = Wt + (size_t)wv * 131072 + lane * 16;
  bf16x8 e0, e1, e2, e3, o0, o1, o2, o3, f0, f1, f2, f3, g0, g1, g2, g3;

#define LOADB(S0, S1, S2, S3, T) do {                                         \
    const uint8_t* q_ = pBw + (size_t)(T) * 4096;                             \
    S0 = *(const bf16x8*)q_;            S1 = *(const bf16x8*)(q_ + 1024);     \
    S2 = *(const bf16x8*)(q_ + 2048);   S3 = *(const bf16x8*)(q_ + 3072);     \
    SEP();                                                                    \
  } while (0)

  LOADB(e0, e1, e2, e3, 0);
  LOADB(o0, o1, o2, o3, 1);
  LOADB(f0, f1, f2, f3, 2);
  __syncthreads();                 // all A writes visible; one barrier total

  // ==== K-loop: 32 k16 steps, no barriers, no LDS writes ====
  f32x16 c00 = {}, c01 = {}, c02 = {}, c03 = {};
  f32x16 c10 = {}, c11 = {}, c12 = {}, c13 = {};
  const int ardA = lo5 << 10;            // row lo5
  const int ardB = (lo5 + 32) << 10;     // row lo5+32

#define COMP(T, S0, S1, S2, S3) do {                                          \
    const int cb_ = (((((T) << 1) | hi1)) ^ lo5) << 4;                        \
    bf16x8 fa0 = *(const bf16x8*)(Ab + ardA + cb_);                           \
    bf16x8 fa1 = *(const bf16x8*)(Ab + ardB + (cb_ ^ 512));                   \
    c00 = MFMA(fa0, S0, c00);  c01 = MFMA(fa0, S1, c01);                      \
    c02 = MFMA(fa0, S2, c02);  c03 = MFMA(fa0, S3, c03);                      \
    c10 = MFMA(fa1, S0, c10);  c11 = MFMA(fa1, S1, c11);                      \
    c12 = MFMA(fa1, S2, c12);  c13 = MFMA(fa1, S3, c13);                      \
  } while (0)

  // sets rotate e,o,f,g; 3-step slack; steady VM(12) (16 in flight -> 12)
#pragma unroll 1
  for (int t = 0; t < 28; t += 4) {
    LOADB(g0, g1, g2, g3, t + 3);  VM(12);  COMP(t,     e0, e1, e2, e3);
    LOADB(e0, e1, e2, e3, t + 4);  VM(12);  COMP(t + 1, o0, o1, o2, o3);
    LOADB(o0, o1, o2, o3, t + 5);  VM(12);  COMP(t + 2, f0, f1, f2, f3);
    LOADB(f0, f1, f2, f3, t + 6);  VM(12);  COMP(t + 3, g0, g1, g2, g3);
  }
  // tail: steps 28..31 (loads e(28), o(29), f(30) in flight; load g(31))
  LOADB(g0, g1, g2, g3, 31);  VM(12);  COMP(28, e0, e1, e2, e3);
  VM(8);   COMP(29, o0, o1, o2, o3);
  VM(4);   COMP(30, f0, f1, f2, f3);
  VM(0);   COMP(31, g0, g1, g2, g3);

  // ==== epilogue: bias + tanh + fp32 store ====
  const int colb = wv * 128 + lo5;
  const float bv0 = Bv[colb];
  const float bv1 = Bv[colb + 32];
  const float bv2 = Bv[colb + 64];
  const float bv3 = Bv[colb + 96];
  const size_t rowbase = (size_t)bm * 64 + (hi1 << 2);

#define EPI(ACC, MI, NF, BV) do {                                             \
    _Pragma("unroll")                                                         \
    for (int r = 0; r < 16; ++r) {                                            \
      const size_t row_ = rowbase + (MI) * 32 + (r & 3) + ((r >> 2) << 3);    \
      Y[row_ * NTOT + colb + (NF) * 32] = fast_tanh((ACC)[r] + (BV));         \
    }                                                                         \
  } while (0)

  EPI(c00, 0, 0, bv0);  EPI(c01, 0, 1, bv1);
  EPI(c02, 0, 2, bv2);  EPI(c03, 0, 3, bv3);
  EPI(c10, 1, 0, bv0);  EPI(c11, 1, 1, bv1);
  EPI(c12, 1, 2, bv2);  EPI(c13, 1, 3, bv3);
}

// ---------------- fallback: R1 kernel (146us), used if ws too small ----------
struct Regs {
  float4 a0,a1,a2,a3,a4,a5,a6,a7;
  float4 u0,u1,u2,u3;
  float4 v0,v1,v2,v3;
};

__global__ __launch_bounds__(256, 2)
void hotdd_fallback(const float* __restrict__ X, const float* __restrict__ W,
                    const float* __restrict__ Bv, float* __restrict__ Y) {
  __shared__ char Ab[128 * 64 * 2];
  __shared__ char Bb[128 * 64 * 2];
  const int d  = blockIdx.x;
  const int bm = ((d >> 5) << 3) | (d & 7);
  const int bn = (d >> 3) & 3;
  const int tid  = threadIdx.x;
  const int lane = tid & 63;
  const int wv   = tid >> 6;
  const int wr   = (wv >> 1) * 64;
  const int wc   = (wv & 1) * 64;
  const int lo5  = lane & 31;
  const int hi1  = lane >> 5;
  const int rs   = lo5 & 7;
  const int am   = tid >> 1;
  const int ah   = tid & 1;
  const int amz  = am & 7;
  const int abase = am * 128;
  const float* Ag = X + (size_t)(bm * 128 + am) * KTOT + ah * 32;
  const int kp = lo5;
  const int ng = wv * 32 + hi1 * 16;
  const float* Bg = W + (size_t)(2 * kp) * NTOT + bn * 128 + ng;

#define LOADR(R, K0) do {                                                     \
    const float* ap_ = Ag + (K0);                                             \
    R.a0 = *(const float4*)(ap_ +  0); R.a1 = *(const float4*)(ap_ +  4);     \
    R.a2 = *(const float4*)(ap_ +  8); R.a3 = *(const float4*)(ap_ + 12);     \
    R.a4 = *(const float4*)(ap_ + 16); R.a5 = *(const float4*)(ap_ + 20);     \
    R.a6 = *(const float4*)(ap_ + 24); R.a7 = *(const float4*)(ap_ + 28);     \
    const float* bp_ = Bg + (size_t)(K0) * NTOT;                              \
    R.u0 = *(const float4*)(bp_ +  0); R.u1 = *(const float4*)(bp_ +  4);     \
    R.u2 = *(const float4*)(bp_ +  8); R.u3 = *(const float4*)(bp_ + 12);     \
    R.v0 = *(const float4*)(bp_ + NTOT +  0); R.v1 = *(const float4*)(bp_ + NTOT +  4); \
    R.v2 = *(const float4*)(bp_ + NTOT +  8); R.v3 = *(const float4*)(bp_ + NTOT + 12); \
  } while (0)

#define ASTF(R, J, P, Q)                                                      \
    *(uint4*)(Ab + abase + (((((ah << 2) + (J)) ^ amz)) << 4)) =              \
      make_uint4(pk2(R.P.x, R.P.y), pk2(R.P.z, R.P.w),                        \
                 pk2(R.Q.x, R.Q.y), pk2(R.Q.z, R.Q.w));
#define BSTF(R, I, UV, C)                                                     \
    *(uint32_t*)(Bb + (ng + (I)) * 128 + ((kp << 2) ^ (((I) & 7) << 4))) =    \
      pk2(R.u##UV.C, R.v##UV.C);

#define STORERF(R) do {                                                       \
    ASTF(R, 0, a0, a1) ASTF(R, 1, a2, a3) ASTF(R, 2, a4, a5) ASTF(R, 3, a6, a7)\
    BSTF(R, 0, 0, x) BSTF(R, 1, 0, y) BSTF(R, 2, 0, z) BSTF(R, 3, 0, w)       \
    BSTF(R, 4, 1, x) BSTF(R, 5, 1, y) BSTF(R, 6, 1, z) BSTF(R, 7, 1, w)       \
    BSTF(R, 8, 2, x) BSTF(R, 9, 2, y) BSTF(R,10, 2, z) BSTF(R,11, 2, w)       \
    BSTF(R,12, 3, x) BSTF(R,13, 3, y) BSTF(R,14, 3, z) BSTF(R,15, 3, w)       \
  } while (0)

  f32x16 acc00 = {}, acc01 = {}, acc10 = {}, acc11 = {};
  const char* Ard0 = Ab + (wr + lo5) * 128;
  const char* Ard1 = Ard0 + 32 * 128;
  const char* Brd0 = Bb + (wc + lo5) * 128;
  const char* Brd1 = Brd0 + 32 * 128;

#define MFMA_PHASE_F() do {                                                   \
    _Pragma("unroll")                                                         \
    for (int kk = 0; kk < 4; ++kk) {                                          \
      const int sb = ((((kk << 1) | hi1) ^ rs) << 4);                         \
      bf16x8 fa0 = *(const bf16x8*)(Ard0 + sb);                               \
      bf16x8 fa1 = *(const bf16x8*)(Ard1 + sb);                               \
      bf16x8 fb0 = *(const bf16x8*)(Brd0 + sb);                               \
      bf16x8 fb1 = *(const bf16x8*)(Brd1 + sb);                               \
      acc00 = MFMA(fa0, fb0, acc00);  acc01 = MFMA(fa0, fb1, acc01);          \
      acc10 = MFMA(fa1, fb0, acc10);  acc11 = MFMA(fa1, fb1, acc11);          \
    }                                                                         \
  } while (0)

  Regs r0, r1;
  LOADR(r0, 0);
#pragma unroll 1
  for (int s = 0; s < 8; s += 2) {
    STORERF(r0);
    __syncthreads();
    LOADR(r1, (s + 1) * 64);
    MFMA_PHASE_F();
    __syncthreads();
    STORERF(r1);
    __syncthreads();
    if (s + 2 < 8) LOADR(r0, (s + 2) * 64);
    MFMA_PHASE_F();
    __syncthreads();
  }

  const int gn0 = bn * 128 + wc + lo5;
  const int gn1 = gn0 + 32;
  const float bv0 = Bv[gn0];
  const float bv1 = Bv[gn1];

#define EPIF(ACC, MI, GN, BVAL) do {                                          \
    _Pragma("unroll")                                                         \
    for (int r = 0; r < 16; ++r) {                                            \
      const int mloc = wr + (MI) * 32 + (hi1 << 2) + ((r >> 2) << 3) + (r & 3);\
      Y[(size_t)(bm * 128 + mloc) * NTOT + (GN)] = fast_tanh((ACC)[r] + (BVAL));\
    }                                                                         \
  } while (0)

  EPIF(acc00, 0, gn0, bv0);
  EPIF(acc01, 0, gn1, bv1);
  EPIF(acc10, 1, gn0, bv0);
  EPIF(acc11, 1, gn1, bv1);
}

extern "C" void kernel_launch(void* const* d_in, const int* in_sizes, int n_in,
                              void* d_out, int out_size, void* d_ws, size_t ws_size,
                              hipStream_t stream) {
  (void)in_sizes; (void)n_in; (void)out_size;
  const float* X = (const float*)d_in[0];
  const float* W = (const float*)d_in[1];
  const float* b = (const float*)d_in[2];
  float* Y = (float*)d_out;
  if (ws_size >= WS_NEEDED) {
    uint8_t* Wt = (uint8_t*)d_ws;
    hipLaunchKernelGGL(cvtW_kernel, dim3(128),  dim3(256), 0, stream, W, Wt);
    hipLaunchKernelGGL(hotdd_fused, dim3(1024), dim3(256), 0, stream, X, Wt, b, Y);
  } else {
    hipLaunchKernelGGL(hotdd_fallback, dim3(2048), dim3(256), 0, stream, X, W, b, Y);
  }
}

// Round 19
// 72.392 us; speedup vs baseline: 1.0989x; 1.0400x over previous
//
#include <hip/hip_runtime.h>
#include <stdint.h>

// Y = tanh(X @ W + b):  M=65536 (8*64*128), K=512, N=512, all fp32.
// R19 = R15 (best, 72.0us) + NON-TEMPORAL X-loads / Y-stores.
// Missed bandwidth term found by cache-budget audit: per XCD, each block
// generation streams 8MB X + 8MB Y through the 4MB L2 -> the 512KB W image
// is continuously evicted -> the K-loop's B reads (512MB aggregate: 1024
// blocks x 512KB) are served from L3, not L2. That stream is the wall
// (explains: idle MFMA/HBM/L2 counters; R16's 2x B = +8us; all R16-R18
// schedule levers null). Fix: mark the two use-once streams `nt` so W stays
// L2-resident. X has zero intra-dispatch reuse (read once by one block);
// Y is never re-read. Cost: ~64MB more HBM fetch (X loses cross-replay L3
// warmth) -- free, HBM interface is 75% idle.
// Everything else byte-identical to R15 (depth-3 B sets, VM(8), 64-row
// blocks, chunk^row swizzle, zero-barrier K-loop).

typedef short bf16x8 __attribute__((ext_vector_type(8)));
typedef float f32x16 __attribute__((ext_vector_type(16)));
typedef float f32x4 __attribute__((ext_vector_type(4)));

#define KTOT 512
#define NTOT 512
#define WT_BYTES   524288ull      // 512*512*2
#define WS_NEEDED  WT_BYTES

__device__ __forceinline__ uint32_t pk2(float a, float b) {
  uint16_t lo = __builtin_bit_cast(uint16_t, (__bf16)a);   // RNE
  uint16_t hi = __builtin_bit_cast(uint16_t, (__bf16)b);
  return (uint32_t)lo | ((uint32_t)hi << 16);
}

__device__ __forceinline__ float fast_tanh(float z) {
  float t = __builtin_amdgcn_exp2f(z * 2.8853900817779268f);
  return 1.0f - 2.0f * __builtin_amdgcn_rcpf(t + 1.0f);
}

#define MFMA(A, B, C) __builtin_amdgcn_mfma_f32_32x32x16_bf16(A, B, C, 0, 0, 0)

// ---- pass 1: W fp32 [k][n] -> bf16 fragment-order image (as R15) ----
// 16B chunk c: lane=c&63, nf=(c>>6)&3, k16=(c>>8)&31, wq=c>>13.
// col = wq*128 + nf*32 + (lane&31); k = k16*16 + (lane>>5)*8 + [0..7].
__global__ __launch_bounds__(256)
void cvtW_kernel(const float* __restrict__ W, uint8_t* __restrict__ Wt) {
  const int c    = blockIdx.x * 256 + threadIdx.x;   // 0..32767
  const int lane = c & 63;
  const int nf   = (c >> 6) & 3;
  const int k16  = (c >> 8) & 31;
  const int wq   = c >> 13;
  const int col  = wq * 128 + nf * 32 + (lane & 31);
  const int kb   = k16 * 16 + (lane >> 5) * 8;
  float e[8];
#pragma unroll
  for (int i = 0; i < 8; ++i) e[i] = W[(size_t)(kb + i) * NTOT + col];
  *(uint4*)(Wt + (size_t)c * 16) =
      make_uint4(pk2(e[0], e[1]), pk2(e[2], e[3]),
                 pk2(e[4], e[5]), pk2(e[6], e[7]));
}

// ---------------- pass 2: one-shot-staged GEMM + bias + tanh ----------------
__global__ __launch_bounds__(256, 2)
void hotdd_fused(const float* __restrict__ X, const uint8_t* __restrict__ Wt,
                 const float* __restrict__ Bv, float* __restrict__ Y) {
  __shared__ uint8_t Ab[65536];   // A panel [64 rows][512 k] bf16, swizzled:
                                  // 16B chunk c of row r stored at slot c ^ r

  const int bm   = blockIdx.x;          // 0..1023 (64-row strips)
  const int tid  = threadIdx.x;
  const int lane = tid & 63;
  const int wv   = tid >> 6;
  const int lo5  = lane & 31;
  const int hi1  = lane >> 5;

#define SEP() asm volatile("" ::: "memory")
#define VM(N) asm volatile("s_waitcnt vmcnt(" #N ")" ::: "memory")

  // ==== prologue: stage A panel (128KB fp32 -> 64KB bf16 LDS), once ====
  // X loads NON-TEMPORAL: use-once stream, keep it out of W's L2/L3 space.
  const float* Xs = X + (size_t)bm * (64 * KTOT);
  const int chunkT = (tid >> 1) & 63;
  const int halfT  = tid & 1;
  const int rbT    = tid >> 7;

  f32x4 p00, p01, p02, p03, p10, p11, p12, p13;

#define NTL(P) __builtin_nontemporal_load((const f32x4*)(P))

#define LOADP(R0, R1, R2, R3, B) do {                                         \
    const float* q_ = Xs + (size_t)(B) * 4096 + tid * 4;                      \
    R0 = NTL(q_);          R1 = NTL(q_ + 1024);                               \
    R2 = NTL(q_ + 2048);   R3 = NTL(q_ + 3072);                               \
    SEP();                                                                    \
  } while (0)

#define CVTP1(R, J) do {                                                      \
    const int row_ = 2 * (J) + rbT;                                           \
    *(uint2*)(Ab + row_ * 1024 + ((chunkT ^ row_) << 4) + halfT * 8) =        \
        make_uint2(pk2(R[0], R[1]), pk2(R[2], R[3]));                         \
  } while (0)
#define CVTP(R0, R1, R2, R3, B) do {                                          \
    CVTP1(R0, 4 * (B));     CVTP1(R1, 4 * (B) + 1);                           \
    CVTP1(R2, 4 * (B) + 2); CVTP1(R3, 4 * (B) + 3);  SEP();                   \
  } while (0)

  LOADP(p00, p01, p02, p03, 0);
  LOADP(p10, p11, p12, p13, 1);
  VM(4); CVTP(p00, p01, p02, p03, 0); LOADP(p00, p01, p02, p03, 2);
  VM(4); CVTP(p10, p11, p12, p13, 1); LOADP(p10, p11, p12, p13, 3);
  VM(4); CVTP(p00, p01, p02, p03, 2); LOADP(p00, p01, p02, p03, 4);
  VM(4); CVTP(p10, p11, p12, p13, 3); LOADP(p10, p11, p12, p13, 5);
  VM(4); CVTP(p00, p01, p02, p03, 4); LOADP(p00, p01, p02, p03, 6);
  VM(4); CVTP(p10, p11, p12, p13, 5); LOADP(p10, p11, p12, p13, 7);
  VM(4); CVTP(p00, p01, p02, p03, 6);
  VM(0); CVTP(p10, p11, p12, p13, 7);

  // ==== B prefetch bootstrap (cacheable -- W image must live in L2) ====
  const uint8_t* pBw = Wt + (size_t)wv * 131072 + lane * 16;
  bf16x8 e0, e1, e2, e3, o0, o1, o2, o3, f0, f1, f2, f3;

#define LOADB(S0, S1, S2, S3, T) do {                                         \
    const uint8_t* q_ = pBw + (size_t)(T) * 4096;                             \
    S0 = *(const bf16x8*)q_;            S1 = *(const bf16x8*)(q_ + 1024);     \
    S2 = *(const bf16x8*)(q_ + 2048);   S3 = *(const bf16x8*)(q_ + 3072);     \
    SEP();                                                                    \
  } while (0)

  LOADB(e0, e1, e2, e3, 0);
  LOADB(o0, o1, o2, o3, 1);
  __syncthreads();                 // all A writes visible; one barrier total

  // ==== K-loop: 32 k16 steps, no barriers, no LDS writes ====
  f32x16 c00 = {}, c01 = {}, c02 = {}, c03 = {};
  f32x16 c10 = {}, c11 = {}, c12 = {}, c13 = {};
  const int ardA = lo5 << 10;            // row lo5
  const int ardB = (lo5 + 32) << 10;     // row lo5+32

#define COMP(T, S0, S1, S2, S3) do {                                          \
    const int cb_ = (((((T) << 1) | hi1)) ^ lo5) << 4;                        \
    bf16x8 fa0 = *(const bf16x8*)(Ab + ardA + cb_);                           \
    bf16x8 fa1 = *(const bf16x8*)(Ab + ardB + (cb_ ^ 512));                   \
    c00 = MFMA(fa0, S0, c00);  c01 = MFMA(fa0, S1, c01);                      \
    c02 = MFMA(fa0, S2, c02);  c03 = MFMA(fa0, S3, c03);                      \
    c10 = MFMA(fa1, S0, c10);  c11 = MFMA(fa1, S1, c11);                      \
    c12 = MFMA(fa1, S2, c12);  c13 = MFMA(fa1, S3, c13);                      \
  } while (0)

#pragma unroll 1
  for (int t = 0; t < 30; t += 3) {      // sets rotate e,o,f; 2-step B slack
    LOADB(f0, f1, f2, f3, t + 2);  VM(8);  COMP(t,     e0, e1, e2, e3);
    LOADB(e0, e1, e2, e3, t + 3);  VM(8);  COMP(t + 1, o0, o1, o2, o3);
    LOADB(o0, o1, o2, o3, t + 4);  VM(8);  COMP(t + 2, f0, f1, f2, f3);
  }
  VM(4);  COMP(30, e0, e1, e2, e3);
  VM(0);  COMP(31, o0, o1, o2, o3);

  // ==== epilogue: bias + tanh + NON-TEMPORAL fp32 store ====
  const int colb = wv * 128 + lo5;
  const float bv0 = Bv[colb];
  const float bv1 = Bv[colb + 32];
  const float bv2 = Bv[colb + 64];
  const float bv3 = Bv[colb + 96];
  const size_t rowbase = (size_t)bm * 64 + (hi1 << 2);

#define EPI(ACC, MI, NF, BV) do {                                             \
    _Pragma("unroll")                                                         \
    for (int r = 0; r < 16; ++r) {                                            \
      const size_t row_ = rowbase + (MI) * 32 + (r & 3) + ((r >> 2) << 3);    \
      __builtin_nontemporal_store(fast_tanh((ACC)[r] + (BV)),                 \
          &Y[row_ * NTOT + colb + (NF) * 32]);                                \
    }                                                                         \
  } while (0)

  EPI(c00, 0, 0, bv0);  EPI(c01, 0, 1, bv1);
  EPI(c02, 0, 2, bv2);  EPI(c03, 0, 3, bv3);
  EPI(c10, 1, 0, bv0);  EPI(c11, 1, 1, bv1);
  EPI(c12, 1, 2, bv2);  EPI(c13, 1, 3, bv3);
}

// ---------------- fallback: R1 kernel (146us), used if ws too small ----------
struct Regs {
  float4 a0,a1,a2,a3,a4,a5,a6,a7;
  float4 u0,u1,u2,u3;
  float4 v0,v1,v2,v3;
};

__global__ __launch_bounds__(256, 2)
void hotdd_fallback(const float* __restrict__ X, const float* __restrict__ W,
                    const float* __restrict__ Bv, float* __restrict__ Y) {
  __shared__ char Ab[128 * 64 * 2];
  __shared__ char Bb[128 * 64 * 2];
  const int d  = blockIdx.x;
  const int bm = ((d >> 5) << 3) | (d & 7);
  const int bn = (d >> 3) & 3;
  const int tid  = threadIdx.x;
  const int lane = tid & 63;
  const int wv   = tid >> 6;
  const int wr   = (wv >> 1) * 64;
  const int wc   = (wv & 1) * 64;
  const int lo5  = lane & 31;
  const int hi1  = lane >> 5;
  const int rs   = lo5 & 7;
  const int am   = tid >> 1;
  const int ah   = tid & 1;
  const int amz  = am & 7;
  const int abase = am * 128;
  const float* Ag = X + (size_t)(bm * 128 + am) * KTOT + ah * 32;
  const int kp = lo5;
  const int ng = wv * 32 + hi1 * 16;
  const float* Bg = W + (size_t)(2 * kp) * NTOT + bn * 128 + ng;

#define LOADR(R, K0) do {                                                     \
    const float* ap_ = Ag + (K0);                                             \
    R.a0 = *(const float4*)(ap_ +  0); R.a1 = *(const float4*)(ap_ +  4);     \
    R.a2 = *(const float4*)(ap_ +  8); R.a3 = *(const float4*)(ap_ + 12);     \
    R.a4 = *(const float4*)(ap_ + 16); R.a5 = *(const float4*)(ap_ + 20);     \
    R.a6 = *(const float4*)(ap_ + 24); R.a7 = *(const float4*)(ap_ + 28);     \
    const float* bp_ = Bg + (size_t)(K0) * NTOT;                              \
    R.u0 = *(const float4*)(bp_ +  0); R.u1 = *(const float4*)(bp_ +  4);     \
    R.u2 = *(const float4*)(bp_ +  8); R.u3 = *(const float4*)(bp_ + 12);     \
    R.v0 = *(const float4*)(bp_ + NTOT +  0); R.v1 = *(const float4*)(bp_ + NTOT +  4); \
    R.v2 = *(const float4*)(bp_ + NTOT +  8); R.v3 = *(const float4*)(bp_ + NTOT + 12); \
  } while (0)

#define ASTF(R, J, P, Q)                                                      \
    *(uint4*)(Ab + abase + (((((ah << 2) + (J)) ^ amz)) << 4)) =              \
      make_uint4(pk2(R.P.x, R.P.y), pk2(R.P.z, R.P.w),                        \
                 pk2(R.Q.x, R.Q.y), pk2(R.Q.z, R.Q.w));
#define BSTF(R, I, UV, C)                                                     \
    *(uint32_t*)(Bb + (ng + (I)) * 128 + ((kp << 2) ^ (((I) & 7) << 4))) =    \
      pk2(R.u##UV.C, R.v##UV.C);

#define STORERF(R) do {                                                       \
    ASTF(R, 0, a0, a1) ASTF(R, 1, a2, a3) ASTF(R, 2, a4, a5) ASTF(R, 3, a6, a7)\
    BSTF(R, 0, 0, x) BSTF(R, 1, 0, y) BSTF(R, 2, 0, z) BSTF(R, 3, 0, w)       \
    BSTF(R, 4, 1, x) BSTF(R, 5, 1, y) BSTF(R, 6, 1, z) BSTF(R, 7, 1, w)       \
    BSTF(R, 8, 2, x) BSTF(R, 9, 2, y) BSTF(R,10, 2, z) BSTF(R,11, 2, w)       \
    BSTF(R,12, 3, x) BSTF(R,13, 3, y) BSTF(R,14, 3, z) BSTF(R,15, 3, w)       \
  } while (0)

  f32x16 acc00 = {}, acc01 = {}, acc10 = {}, acc11 = {};
  const char* Ard0 = Ab + (wr + lo5) * 128;
  const char* Ard1 = Ard0 + 32 * 128;
  const char* Brd0 = Bb + (wc + lo5) * 128;
  const char* Brd1 = Brd0 + 32 * 128;

#define MFMA_PHASE_F() do {                                                   \
    _Pragma("unroll")                                                         \
    for (int kk = 0; kk < 4; ++kk) {                                          \
      const int sb = ((((kk << 1) | hi1) ^ rs) << 4);                         \
      bf16x8 fa0 = *(const bf16x8*)(Ard0 + sb);                               \
      bf16x8 fa1 = *(const bf16x8*)(Ard1 + sb);                               \
      bf16x8 fb0 = *(const bf16x8*)(Brd0 + sb);                               \
      bf16x8 fb1 = *(const bf16x8*)(Brd1 + sb);                               \
      acc00 = MFMA(fa0, fb0, acc00);  acc01 = MFMA(fa0, fb1, acc01);          \
      acc10 = MFMA(fa1, fb0, acc10);  acc11 = MFMA(fa1, fb1, acc11);          \
    }                                                                         \
  } while (0)

  Regs r0, r1;
  LOADR(r0, 0);
#pragma unroll 1
  for (int s = 0; s < 8; s += 2) {
    STORERF(r0);
    __syncthreads();
    LOADR(r1, (s + 1) * 64);
    MFMA_PHASE_F();
    __syncthreads();
    STORERF(r1);
    __syncthreads();
    if (s + 2 < 8) LOADR(r0, (s + 2) * 64);
    MFMA_PHASE_F();
    __syncthreads();
  }

  const int gn0 = bn * 128 + wc + lo5;
  const int gn1 = gn0 + 32;
  const float bv0 = Bv[gn0];
  const float bv1 = Bv[gn1];

#define EPIF(ACC, MI, GN, BVAL) do {                                          \
    _Pragma("unroll")                                                         \
    for (int r = 0; r < 16; ++r) {                                            \
      const int mloc = wr + (MI) * 32 + (hi1 << 2) + ((r >> 2) << 3) + (r & 3);\
      Y[(size_t)(bm * 128 + mloc) * NTOT + (GN)] = fast_tanh((ACC)[r] + (BVAL));\
    }                                                                         \
  } while (0)

  EPIF(acc00, 0, gn0, bv0);
  EPIF(acc01, 0, gn1, bv1);
  EPIF(acc10, 1, gn0, bv0);
  EPIF(acc11, 1, gn1, bv1);
}

extern "C" void kernel_launch(void* const* d_in, const int* in_sizes, int n_in,
                              void* d_out, int out_size, void* d_ws, size_t ws_size,
                              hipStream_t stream) {
  (void)in_sizes; (void)n_in; (void)out_size;
  const float* X = (const float*)d_in[0];
  const float* W = (const float*)d_in[1];
  const float* b = (const float*)d_in[2];
  float* Y = (float*)d_out;
  if (ws_size >= WS_NEEDED) {
    uint8_t* Wt = (uint8_t*)d_ws;
    hipLaunchKernelGGL(cvtW_kernel, dim3(128),  dim3(256), 0, stream, W, Wt);
    hipLaunchKernelGGL(hotdd_fused, dim3(1024), dim3(256), 0, stream, X, Wt, b, Y);
  } else {
    hipLaunchKernelGGL(hotdd_fallback, dim3(2048), dim3(256), 0, stream, X, W, b, Y);
  }
}

// Round 20
// 70.525 us; speedup vs baseline: 1.1280x; 1.0265x over previous
//
#include <hip/hip_runtime.h>
#include <stdint.h>

// Y = tanh(X @ W + b):  M=65536 (8*64*128), K=512, N=512, all fp32.
// R20: PERSISTENT BLOCKS + CROSS-STRIP SOFTWARE PIPELINE.
// R15-R19 post-mortem: 72us = mandatory HBM stream (~41us/CU) + L2 B-stream
// (~15us) + MFMA (3.4us) with POOR phase overlap (2 stochastic blocks/CU).
// Fix: grid=256 (1 block/CU, LDS 128KB ping-pong), 4 strips per block.
// K-loop of strip s interleaves HBM-load+cvt of strip s+1 (1 batch per
// 4 steps, ~4-step slack) -> the HBM read stream runs continuously under
// the L2-bound K-loops BY CONSTRUCTION. Epilogue stores fire-and-forget.
// vmcnt discipline (in-order retirement, derived exactly):
//   pref groups:  G0 VM(8) [retire A(g),B(t)] -> CVTP(g), COMP(t), LOADP(g+1)
//                 G1 VM(12) [B(t+1)]  G2 VM(12) [B(t+2)]
//                 G3 VM(8)  [A(g+1) forced + B(t+3)]
//   non-pref:     VM(8) at all 4 positions.
//   tails: 8 -> 8 -> 4 -> 0.  Bootstrap/stores handled conservatively
//   (first VM(8) of each strip drains prior stores; counts stay safe).
// (256,1): no VGPR cap (~110 VGPR + 128 AGPR, no spill possible).

typedef short bf16x8 __attribute__((ext_vector_type(8)));
typedef float f32x16 __attribute__((ext_vector_type(16)));

#define KTOT 512
#define NTOT 512
#define WT_BYTES   524288ull      // 512*512*2
#define WS_NEEDED  WT_BYTES

__device__ __forceinline__ uint32_t pk2(float a, float b) {
  uint16_t lo = __builtin_bit_cast(uint16_t, (__bf16)a);   // RNE
  uint16_t hi = __builtin_bit_cast(uint16_t, (__bf16)b);
  return (uint32_t)lo | ((uint32_t)hi << 16);
}

__device__ __forceinline__ float fast_tanh(float z) {
  float t = __builtin_amdgcn_exp2f(z * 2.8853900817779268f);
  return 1.0f - 2.0f * __builtin_amdgcn_rcpf(t + 1.0f);
}

#define MFMA(A, B, C) __builtin_amdgcn_mfma_f32_32x32x16_bf16(A, B, C, 0, 0, 0)

// ---- pass 1: W fp32 [k][n] -> bf16 fragment-order image (as R15) ----
__global__ __launch_bounds__(256)
void cvtW_kernel(const float* __restrict__ W, uint8_t* __restrict__ Wt) {
  const int c    = blockIdx.x * 256 + threadIdx.x;   // 0..32767
  const int lane = c & 63;
  const int nf   = (c >> 6) & 3;
  const int k16  = (c >> 8) & 31;
  const int wq   = c >> 13;
  const int col  = wq * 128 + nf * 32 + (lane & 31);
  const int kb   = k16 * 16 + (lane >> 5) * 8;
  float e[8];
#pragma unroll
  for (int i = 0; i < 8; ++i) e[i] = W[(size_t)(kb + i) * NTOT + col];
  *(uint4*)(Wt + (size_t)c * 16) =
      make_uint4(pk2(e[0], e[1]), pk2(e[2], e[3]),
                 pk2(e[4], e[5]), pk2(e[6], e[7]));
}

// ---------------- pass 2: persistent pipelined GEMM + bias + tanh ----------
__global__ __launch_bounds__(256, 1)
void hotdd_fused(const float* __restrict__ X, const uint8_t* __restrict__ Wt,
                 const float* __restrict__ Bv, float* __restrict__ Y) {
  __shared__ uint8_t Ab[131072];  // 2 x 64KB panels [64 rows][512 k] bf16,
                                  // 16B chunk c of row r at slot c ^ r

  const int bm   = blockIdx.x;          // 0..255; strips bm + 256*s, s=0..3
  const int tid  = threadIdx.x;
  const int lane = tid & 63;
  const int wv   = tid >> 6;
  const int lo5  = lane & 31;
  const int hi1  = lane >> 5;
  const int chunkT = (tid >> 1) & 63;
  const int halfT  = tid & 1;
  const int rbT    = tid >> 7;

#define SEP() asm volatile("" ::: "memory")
#define VM(N) asm volatile("s_waitcnt vmcnt(" #N ")" ::: "memory")

  float4 p00, p01, p02, p03, p10, p11, p12, p13;

#define PLOAD(R0, R1, R2, R3, BASE, B) do {                                   \
    const float* q_ = (BASE) + (size_t)(B) * 4096 + tid * 4;                  \
    R0 = *(const float4*)q_;          R1 = *(const float4*)(q_ + 1024);       \
    R2 = *(const float4*)(q_ + 2048); R3 = *(const float4*)(q_ + 3072);       \
    SEP();                                                                    \
  } while (0)

#define PCVT1(R, ROW, DST)                                                    \
    *(uint2*)(Ab + (DST) + (ROW) * 1024 + (((chunkT) ^ (ROW)) << 4)           \
              + halfT * 8) = make_uint2(pk2(R.x, R.y), pk2(R.z, R.w));
#define PCVT(R0, R1, R2, R3, B, DST) do {                                     \
    const int rb_ = 8 * (B) + rbT;                                            \
    PCVT1(R0, rb_,     DST)  PCVT1(R1, rb_ + 2, DST)                          \
    PCVT1(R2, rb_ + 4, DST)  PCVT1(R3, rb_ + 6, DST)  SEP();                  \
  } while (0)

  // ==== strip-0 prologue: stage panel into offset 0 (depth-2, R15-exact) ====
  const float* Xs0 = X + (size_t)bm * (64 * KTOT);
  PLOAD(p00, p01, p02, p03, Xs0, 0);
  PLOAD(p10, p11, p12, p13, Xs0, 1);
  VM(4); PCVT(p00, p01, p02, p03, 0, 0); PLOAD(p00, p01, p02, p03, Xs0, 2);
  VM(4); PCVT(p10, p11, p12, p13, 1, 0); PLOAD(p10, p11, p12, p13, Xs0, 3);
  VM(4); PCVT(p00, p01, p02, p03, 2, 0); PLOAD(p00, p01, p02, p03, Xs0, 4);
  VM(4); PCVT(p10, p11, p12, p13, 3, 0); PLOAD(p10, p11, p12, p13, Xs0, 5);
  VM(4); PCVT(p00, p01, p02, p03, 4, 0); PLOAD(p00, p01, p02, p03, Xs0, 6);
  VM(4); PCVT(p10, p11, p12, p13, 5, 0); PLOAD(p10, p11, p12, p13, Xs0, 7);
  VM(4); PCVT(p00, p01, p02, p03, 6, 0);
  VM(0); PCVT(p10, p11, p12, p13, 7, 0);

  // ==== B fragment stream (same 512KB W image for every strip) ====
  const uint8_t* pBw = Wt + (size_t)wv * 131072 + lane * 16;
  bf16x8 bA0,bA1,bA2,bA3, bB0,bB1,bB2,bB3, bC0,bC1,bC2,bC3, bD0,bD1,bD2,bD3;

#define LODB(S0, S1, S2, S3, T) do {                                          \
    const uint8_t* q_ = pBw + (size_t)(T) * 4096;                             \
    S0 = *(const bf16x8*)q_;            S1 = *(const bf16x8*)(q_ + 1024);     \
    S2 = *(const bf16x8*)(q_ + 2048);   S3 = *(const bf16x8*)(q_ + 3072);     \
    SEP();                                                                    \
  } while (0)

  // bootstrap strip 0 + batch 0 of strip 1
  LODB(bA0,bA1,bA2,bA3, 0);
  LODB(bB0,bB1,bB2,bB3, 1);
  PLOAD(p00, p01, p02, p03, X + (size_t)(bm + 256) * (64 * KTOT), 0);
  __syncthreads();               // panel 0 visible (drains vmcnt too - safe)

  f32x16 c00 = {}, c01 = {}, c02 = {}, c03 = {};
  f32x16 c10 = {}, c11 = {}, c12 = {}, c13 = {};

#define COMP(T, S0, S1, S2, S3, CUR) do {                                     \
    const int cb_ = (((((T) << 1) | hi1)) ^ lo5) << 4;                        \
    bf16x8 fa0 = *(const bf16x8*)(Ab + (CUR) + (lo5 << 10) + cb_);            \
    bf16x8 fa1 = *(const bf16x8*)(Ab + (CUR) + ((lo5 + 32) << 10)             \
                                  + (cb_ ^ 512));                             \
    c00 = MFMA(fa0, S0, c00);  c01 = MFMA(fa0, S1, c01);                      \
    c02 = MFMA(fa0, S2, c02);  c03 = MFMA(fa0, S3, c03);                      \
    c10 = MFMA(fa1, S0, c10);  c11 = MFMA(fa1, S1, c11);                      \
    c12 = MFMA(fa1, S2, c12);  c13 = MFMA(fa1, S3, c13);                      \
  } while (0)

  const int colb = wv * 128 + lo5;
  const float bv0 = Bv[colb];
  const float bv1 = Bv[colb + 32];
  const float bv2 = Bv[colb + 64];
  const float bv3 = Bv[colb + 96];

#define EPI1(ACC, MI, NF, BV, RB) do {                                        \
    _Pragma("unroll")                                                         \
    for (int r = 0; r < 16; ++r) {                                            \
      const size_t row_ = (RB) + (MI) * 32 + (r & 3) + ((r >> 2) << 3);       \
      Y[row_ * NTOT + colb + (NF) * 32] = fast_tanh((ACC)[r] + (BV));         \
    }                                                                         \
  } while (0)

  int curOff = 0;

#pragma unroll 1
  for (int s = 0; s < 4; ++s) {
    const int nxtOff = curOff ^ 65536;
    const float* pXn = X + (size_t)(bm + (((s + 1) & 3) << 8)) * (64 * KTOT);

    if (s < 3) {
      // ---- pref K-loop: compute strip s, stage strip s+1 ----
#pragma unroll 1
      for (int g = 0; g < 7; ++g) {
        const int t_ = g << 2;
        LODB(bC0,bC1,bC2,bC3, t_ + 2);
        VM(8);                                  // retire A(g), B(t)
        PCVT(p00, p01, p02, p03, g, nxtOff);
        COMP(t_,     bA0,bA1,bA2,bA3, curOff);
        PLOAD(p00, p01, p02, p03, pXn, g + 1);
        LODB(bD0,bD1,bD2,bD3, t_ + 3);
        VM(12);                                 // retire B(t+1)
        COMP(t_ + 1, bB0,bB1,bB2,bB3, curOff);
        LODB(bA0,bA1,bA2,bA3, t_ + 4);
        VM(12);                                 // retire B(t+2)
        COMP(t_ + 2, bC0,bC1,bC2,bC3, curOff);
        LODB(bB0,bB1,bB2,bB3, t_ + 5);
        VM(8);                                  // retire A(g+1)+B(t+3)
        COMP(t_ + 3, bD0,bD1,bD2,bD3, curOff);
      }
      // tail group t=28..31
      LODB(bC0,bC1,bC2,bC3, 30);
      VM(8);  PCVT(p00, p01, p02, p03, 7, nxtOff);
      COMP(28, bA0,bA1,bA2,bA3, curOff);
      LODB(bD0,bD1,bD2,bD3, 31);
      VM(8);  COMP(29, bB0,bB1,bB2,bB3, curOff);
      VM(4);  COMP(30, bC0,bC1,bC2,bC3, curOff);
      VM(0);  COMP(31, bD0,bD1,bD2,bD3, curOff);
    } else {
      // ---- last strip: pure K-loop ----
#pragma unroll 1
      for (int g = 0; g < 7; ++g) {
        const int t_ = g << 2;
        LODB(bC0,bC1,bC2,bC3, t_ + 2);  VM(8);
        COMP(t_,     bA0,bA1,bA2,bA3, curOff);
        LODB(bD0,bD1,bD2,bD3, t_ + 3);  VM(8);
        COMP(t_ + 1, bB0,bB1,bB2,bB3, curOff);
        LODB(bA0,bA1,bA2,bA3, t_ + 4);  VM(8);
        COMP(t_ + 2, bC0,bC1,bC2,bC3, curOff);
        LODB(bB0,bB1,bB2,bB3, t_ + 5);  VM(8);
        COMP(t_ + 3, bD0,bD1,bD2,bD3, curOff);
      }
      LODB(bC0,bC1,bC2,bC3, 30);
      VM(8);  COMP(28, bA0,bA1,bA2,bA3, curOff);
      LODB(bD0,bD1,bD2,bD3, 31);
      VM(8);  COMP(29, bB0,bB1,bB2,bB3, curOff);
      VM(4);  COMP(30, bC0,bC1,bC2,bC3, curOff);
      VM(0);  COMP(31, bD0,bD1,bD2,bD3, curOff);
    }

    __syncthreads();               // strip s+1 panel complete & visible

    if (s < 2) {                   // batch 0 of strip s+2 (for next K-loop)
      const float* pXn2 = X + (size_t)(bm + ((s + 2) << 8)) * (64 * KTOT);
      PLOAD(p00, p01, p02, p03, pXn2, 0);
    }

    // ---- epilogue strip s (stores fire-and-forget) ----
    {
      const size_t rb = (size_t)(bm + (s << 8)) * 64 + (hi1 << 2);
      EPI1(c00, 0, 0, bv0, rb);  EPI1(c01, 0, 1, bv1, rb);
      EPI1(c02, 0, 2, bv2, rb);  EPI1(c03, 0, 3, bv3, rb);
      EPI1(c10, 1, 0, bv0, rb);  EPI1(c11, 1, 1, bv1, rb);
      EPI1(c12, 1, 2, bv2, rb);  EPI1(c13, 1, 3, bv3, rb);
      c00 = (f32x16){}; c01 = (f32x16){}; c02 = (f32x16){}; c03 = (f32x16){};
      c10 = (f32x16){}; c11 = (f32x16){}; c12 = (f32x16){}; c13 = (f32x16){};
    }

    if (s < 3) {                   // B bootstrap for next strip (same image)
      LODB(bA0,bA1,bA2,bA3, 0);
      LODB(bB0,bB1,bB2,bB3, 1);
    }
    curOff = nxtOff;
  }
}

// ---------------- fallback: R1 kernel (146us), used if ws too small ----------
struct Regs {
  float4 a0,a1,a2,a3,a4,a5,a6,a7;
  float4 u0,u1,u2,u3;
  float4 v0,v1,v2,v3;
};

__global__ __launch_bounds__(256, 2)
void hotdd_fallback(const float* __restrict__ X, const float* __restrict__ W,
                    const float* __restrict__ Bv, float* __restrict__ Y) {
  __shared__ char Ab[128 * 64 * 2];
  __shared__ char Bb[128 * 64 * 2];
  const int d  = blockIdx.x;
  const int bm = ((d >> 5) << 3) | (d & 7);
  const int bn = (d >> 3) & 3;
  const int tid  = threadIdx.x;
  const int lane = tid & 63;
  const int wv   = tid >> 6;
  const int wr   = (wv >> 1) * 64;
  const int wc   = (wv & 1) * 64;
  const int lo5  = lane & 31;
  const int hi1  = lane >> 5;
  const int rs   = lo5 & 7;
  const int am   = tid >> 1;
  const int ah   = tid & 1;
  const int amz  = am & 7;
  const int abase = am * 128;
  const float* Ag = X + (size_t)(bm * 128 + am) * KTOT + ah * 32;
  const int kp = lo5;
  const int ng = wv * 32 + hi1 * 16;
  const float* Bg = W + (size_t)(2 * kp) * NTOT + bn * 128 + ng;

#define LOADR(R, K0) do {                                                     \
    const float* ap_ = Ag + (K0);                                             \
    R.a0 = *(const float4*)(ap_ +  0); R.a1 = *(const float4*)(ap_ +  4);     \
    R.a2 = *(const float4*)(ap_ +  8); R.a3 = *(const float4*)(ap_ + 12);     \
    R.a4 = *(const float4*)(ap_ + 16); R.a5 = *(const float4*)(ap_ + 20);     \
    R.a6 = *(const float4*)(ap_ + 24); R.a7 = *(const float4*)(ap_ + 28);     \
    const float* bp_ = Bg + (size_t)(K0) * NTOT;                              \
    R.u0 = *(const float4*)(bp_ +  0); R.u1 = *(const float4*)(bp_ +  4);     \
    R.u2 = *(const float4*)(bp_ +  8); R.u3 = *(const float4*)(bp_ + 12);     \
    R.v0 = *(const float4*)(bp_ + NTOT +  0); R.v1 = *(const float4*)(bp_ + NTOT +  4); \
    R.v2 = *(const float4*)(bp_ + NTOT +  8); R.v3 = *(const float4*)(bp_ + NTOT + 12); \
  } while (0)

#define ASTF(R, J, P, Q)                                                      \
    *(uint4*)(Ab + abase + (((((ah << 2) + (J)) ^ amz)) << 4)) =              \
      make_uint4(pk2(R.P.x, R.P.y), pk2(R.P.z, R.P.w),                        \
                 pk2(R.Q.x, R.Q.y), pk2(R.Q.z, R.Q.w));
#define BSTF(R, I, UV, C)                                                     \
    *(uint32_t*)(Bb + (ng + (I)) * 128 + ((kp << 2) ^ (((I) & 7) << 4))) =    \
      pk2(R.u##UV.C, R.v##UV.C);

#define STORERF(R) do {                                                       \
    ASTF(R, 0, a0, a1) ASTF(R, 1, a2, a3) ASTF(R, 2, a4, a5) ASTF(R, 3, a6, a7)\
    BSTF(R, 0, 0, x) BSTF(R, 1, 0, y) BSTF(R, 2, 0, z) BSTF(R, 3, 0, w)       \
    BSTF(R, 4, 1, x) BSTF(R, 5, 1, y) BSTF(R, 6, 1, z) BSTF(R, 7, 1, w)       \
    BSTF(R, 8, 2, x) BSTF(R, 9, 2, y) BSTF(R,10, 2, z) BSTF(R,11, 2, w)       \
    BSTF(R,12, 3, x) BSTF(R,13, 3, y) BSTF(R,14, 3, z) BSTF(R,15, 3, w)       \
  } while (0)

  f32x16 acc00 = {}, acc01 = {}, acc10 = {}, acc11 = {};
  const char* Ard0 = Ab + (wr + lo5) * 128;
  const char* Ard1 = Ard0 + 32 * 128;
  const char* Brd0 = Bb + (wc + lo5) * 128;
  const char* Brd1 = Brd0 + 32 * 128;

#define MFMA_PHASE_F() do {                                                   \
    _Pragma("unroll")                                                         \
    for (int kk = 0; kk < 4; ++kk) {                                          \
      const int sb = ((((kk << 1) | hi1) ^ rs) << 4);                         \
      bf16x8 fa0 = *(const bf16x8*)(Ard0 + sb);                               \
      bf16x8 fa1 = *(const bf16x8*)(Ard1 + sb);                               \
      bf16x8 fb0 = *(const bf16x8*)(Brd0 + sb);                               \
      bf16x8 fb1 = *(const bf16x8*)(Brd1 + sb);                               \
      acc00 = MFMA(fa0, fb0, acc00);  acc01 = MFMA(fa0, fb1, acc01);          \
      acc10 = MFMA(fa1, fb0, acc10);  acc11 = MFMA(fa1, fb1, acc11);          \
    }                                                                         \
  } while (0)

  Regs r0, r1;
  LOADR(r0, 0);
#pragma unroll 1
  for (int s = 0; s < 8; s += 2) {
    STORERF(r0);
    __syncthreads();
    LOADR(r1, (s + 1) * 64);
    MFMA_PHASE_F();
    __syncthreads();
    STORERF(r1);
    __syncthreads();
    if (s + 2 < 8) LOADR(r0, (s + 2) * 64);
    MFMA_PHASE_F();
    __syncthreads();
  }

  const int gn0 = bn * 128 + wc + lo5;
  const int gn1 = gn0 + 32;
  const float bv0 = Bv[gn0];
  const float bv1 = Bv[gn1];

#define EPIF(ACC, MI, GN, BVAL) do {                                          \
    _Pragma("unroll")                                                         \
    for (int r = 0; r < 16; ++r) {                                            \
      const int mloc = wr + (MI) * 32 + (hi1 << 2) + ((r >> 2) << 3) + (r & 3);\
      Y[(size_t)(bm * 128 + mloc) * NTOT + (GN)] = fast_tanh((ACC)[r] + (BVAL));\
    }                                                                         \
  } while (0)

  EPIF(acc00, 0, gn0, bv0);
  EPIF(acc01, 0, gn1, bv1);
  EPIF(acc10, 1, gn0, bv0);
  EPIF(acc11, 1, gn1, bv1);
}

extern "C" void kernel_launch(void* const* d_in, const int* in_sizes, int n_in,
                              void* d_out, int out_size, void* d_ws, size_t ws_size,
                              hipStream_t stream) {
  (void)in_sizes; (void)n_in; (void)out_size;
  const float* X = (const float*)d_in[0];
  const float* W = (const float*)d_in[1];
  const float* b = (const float*)d_in[2];
  float* Y = (float*)d_out;
  if (ws_size >= WS_NEEDED) {
    uint8_t* Wt = (uint8_t*)d_ws;
    hipLaunchKernelGGL(cvtW_kernel, dim3(128), dim3(256), 0, stream, W, Wt);
    hipLaunchKernelGGL(hotdd_fused, dim3(256), dim3(256), 0, stream, X, Wt, b, Y);
  } else {
    hipLaunchKernelGGL(hotdd_fallback, dim3(2048), dim3(256), 0, stream, X, W, b, Y);
  }
}